// Round 14
// baseline (707.616 us; speedup 1.0000x reference)
//
#include <hip/hip_runtime.h>
#include <math.h>

#define H 128
#define BN_EPS 1e-5f

typedef float float4v __attribute__((ext_vector_type(4)));
typedef short short8v __attribute__((ext_vector_type(8)));
typedef unsigned short ushort4v __attribute__((ext_vector_type(4)));
typedef unsigned short ushort8v __attribute__((ext_vector_type(8)));

__device__ inline unsigned short bf16h(float x) {
    unsigned int u = __float_as_uint(x);
    return (unsigned short)((u + 0x7fffu + ((u >> 16) & 1u)) >> 16);
}
__device__ inline float bf16f(unsigned short h) {
    return __uint_as_float(((unsigned int)h) << 16);
}

// ---------------- Atom encoder: bf16 output h0 -------------------------------
__global__ __launch_bounds__(256) void enc_kernel(const int* __restrict__ x,
    const float* __restrict__ table, unsigned short* __restrict__ h, int N)
{
    int i = blockIdx.x * 256 + threadIdx.x;
    int node = i >> 5;
    if (node >= N) return;
    int c4 = i & 31;
    const int offs[9] = {0, 119, 123, 135, 147, 157, 163, 169, 171};
    const int* xr = x + node * 9;
    float4 s = make_float4(0.f, 0.f, 0.f, 0.f);
#pragma unroll
    for (int f = 0; f < 9; ++f) {
        float4 v = ((const float4*)(table + (size_t)(xr[f] + offs[f]) * H))[c4];
        s.x += v.x; s.y += v.y; s.z += v.z; s.w += v.w;
    }
    ushort4v o = {bf16h(s.x), bf16h(s.y), bf16h(s.z), bf16h(s.w)};
    *(ushort4v*)&h[(size_t)node * H + c4 * 4] = o;
}

// ---------------- degree (in-degree over col), int atomics -------------------
__global__ __launch_bounds__(256) void deg_kernel(const int* __restrict__ col,
                                                  int* __restrict__ deg, int E)
{
    int e = blockIdx.x * 256 + threadIdx.x;
    if (e < E) atomicAdd(&deg[col[e]], 1);
}

__global__ __launch_bounds__(256) void dis_kernel(const int* __restrict__ deg,
                                                  float* __restrict__ dis, int N)
{
    int i = blockIdx.x * 256 + threadIdx.x;
    if (i < N) dis[i] = rsqrtf((float)deg[i] + 1.0f);  // +1 = self loop
}

// ---------------- scan step 1: per-block sums of deg -------------------------
__global__ __launch_bounds__(256) void scan1_kernel(const int* __restrict__ deg,
    int* __restrict__ blockSums, int N)
{
    __shared__ int s[256];
    int t = threadIdx.x;
    int g = blockIdx.x * 256 + t;
    s[t] = (g < N) ? deg[g] : 0;
    __syncthreads();
#pragma unroll
    for (int off = 128; off > 0; off >>= 1) {
        if (t < off) s[t] += s[t + off];
        __syncthreads();
    }
    if (t == 0) blockSums[blockIdx.x] = s[0];
}

// ---------------- scan step 2: exclusive scan of block sums (<=512) ----------
__global__ __launch_bounds__(512) void scan2_kernel(int* __restrict__ blockSums, int NB)
{
    __shared__ int s[512];
    int t = threadIdx.x;
    int own = (t < NB) ? blockSums[t] : 0;
    s[t] = own;
    __syncthreads();
    for (int off = 1; off < 512; off <<= 1) {
        int v = (t >= off) ? s[t - off] : 0;
        __syncthreads();
        s[t] += v;
        __syncthreads();
    }
    if (t < NB) blockSums[t] = s[t] - own;  // exclusive
}

// ---------------- scan step 3: final row_ptr ---------------------------------
__global__ __launch_bounds__(256) void scan3_kernel(const int* __restrict__ deg,
    const int* __restrict__ blockOff, int* __restrict__ row_ptr, int N, int E)
{
    __shared__ int s[256];
    int t = threadIdx.x;
    int g = blockIdx.x * 256 + t;
    int own = (g < N) ? deg[g] : 0;
    s[t] = own;
    __syncthreads();
    for (int off = 1; off < 256; off <<= 1) {
        int v = (t >= off) ? s[t - off] : 0;
        __syncthreads();
        s[t] += v;
        __syncthreads();
    }
    if (g < N) row_ptr[g] = blockOff[blockIdx.x] + s[t] - own;
    if (g == N - 1) row_ptr[N] = E;
}

// ---------------- fill CSR: edge_data[pos] = {src_byte_offset, norm} ---------
__global__ __launch_bounds__(256) void fill_kernel(const int* __restrict__ row,
    const int* __restrict__ col, const int* __restrict__ row_ptr,
    int* __restrict__ cnt, const float* __restrict__ dis,
    float2* __restrict__ edge_data, int E)
{
    int e = blockIdx.x * 256 + threadIdx.x;
    if (e >= E) return;
    int r = row[e], c = col[e];
    int pos = row_ptr[c] + atomicAdd(&cnt[c], 1);
    // store src * 256 (byte offset of bf16 row of H=128) for cheap gather addressing
    edge_data[pos] = make_float2(__int_as_float(r << 8), dis[r] * dis[c]);
}

// ---------------- W prep: Wt_hi/lo[l][n][k] = bf16split(W[l][k][n]) ----------
__global__ __launch_bounds__(128) void wprep_kernel(const float* __restrict__ W,
    unsigned short* __restrict__ wt, int L)
{
    int b = blockIdx.x;
    int l = b >> 7, k = b & 127;
    int n = threadIdx.x;
    float x = W[(size_t)l * H * H + (size_t)k * H + n];
    unsigned short hi = bf16h(x);
    unsigned short lo = bf16h(x - bf16f(hi));
    unsigned short* base = wt + (size_t)l * 2 * H * H;
    base[(size_t)n * H + k] = hi;                       // hi block [n][k]
    base[(size_t)H * H + (size_t)n * H + k] = lo;       // lo block [n][k]
}

// ---------------- MFMA GEMM + fused prev-layer BN-apply, 64-row tile ---------
#define LSTR 40  // LDS row stride in shorts (padded from 32)
__global__ __launch_bounds__(256) void gemm_mfma_kernel(
    const unsigned short* __restrict__ Ain, const unsigned short* __restrict__ Cin,
    const float* __restrict__ stats, const unsigned short* __restrict__ wthi,
    unsigned short* __restrict__ outB, unsigned short* __restrict__ Aout,
    int N, int fuse)
{
    __shared__ unsigned short Ab[64 * LSTR];
    __shared__ unsigned short Bh[128 * LSTR];
    __shared__ unsigned short Bl[128 * LSTR];

    const unsigned short* wtlo = wthi + H * H;
    const int tx = threadIdx.x;
    const int rowBase = blockIdx.x * 64;
    const int lane = tx & 63;
    const int w = tx >> 6;
    const int cw = w * 32;           // 32-col strip per wave
    const int mrow = lane & 15;
    const int quad = lane >> 4;

    const float4* sc4 = (const float4*)(stats + 2 * H);
    const float4* sh4 = (const float4*)(stats + 3 * H);

    float4v acc[4][2];
#pragma unroll
    for (int i = 0; i < 4; ++i)
#pragma unroll
        for (int j = 0; j < 2; ++j)
            acc[i][j] = (float4v)(0.f);

    ushort4v aPre[2][2], cPre[2][2];
    ushort8v whPre[2][2], wlPre[2][2];

    auto loadChunk = [&](int kk, int buf) {
#pragma unroll
        for (int i = 0; i < 2; ++i) {
            int idx = i * 256 + tx;   // 0..511
            int r = idx >> 3;         // 0..63
            int f4 = idx & 7;
            int gr = rowBase + r;
            ushort4v av = {0, 0, 0, 0}, cv = {0, 0, 0, 0};
            if (gr < N) {
                av = *(const ushort4v*)&Ain[(size_t)gr * H + kk + f4 * 4];
                if (fuse) cv = *(const ushort4v*)&Cin[(size_t)gr * H + kk + f4 * 4];
            }
            aPre[buf][i] = av;
            cPre[buf][i] = cv;
        }
#pragma unroll
        for (int i = 0; i < 2; ++i) {
            int idx = i * 256 + tx;   // 0..511
            int n = idx >> 2;         // 0..127
            int q = idx & 3;
            whPre[buf][i] = *(const ushort8v*)&wthi[(size_t)n * H + kk + q * 8];
            wlPre[buf][i] = *(const ushort8v*)&wtlo[(size_t)n * H + kk + q * 8];
        }
    };

    loadChunk(0, 0);

#pragma unroll
    for (int c = 0; c < 4; ++c) {
        const int kk = c * 32;
        const int buf = c & 1;
        __syncthreads();
#pragma unroll
        for (int i = 0; i < 2; ++i) {
            int idx = i * 256 + tx;
            int r = idx >> 3;
            int f4 = idx & 7;
            int gr = rowBase + r;
            ushort4v hv = aPre[buf][i];
            if (fuse) {
                int cq = (kk >> 2) + f4;
                float4 sc = sc4[cq];
                float4 sh = sh4[cq];
                ushort4v cv = cPre[buf][i];
                float ox = fmaxf(bf16f(cv[0]) * sc.x + sh.x, 0.f) + bf16f(hv[0]);
                float oy = fmaxf(bf16f(cv[1]) * sc.y + sh.y, 0.f) + bf16f(hv[1]);
                float oz = fmaxf(bf16f(cv[2]) * sc.z + sh.z, 0.f) + bf16f(hv[2]);
                float ow = fmaxf(bf16f(cv[3]) * sc.w + sh.w, 0.f) + bf16f(hv[3]);
                hv[0] = bf16h(ox); hv[1] = bf16h(oy);
                hv[2] = bf16h(oz); hv[3] = bf16h(ow);
                if (gr < N)
                    *(ushort4v*)&Aout[(size_t)gr * H + kk + f4 * 4] = hv;
            }
            *(ushort4v*)&Ab[r * LSTR + f4 * 4] = hv;
        }
#pragma unroll
        for (int i = 0; i < 2; ++i) {
            int idx = i * 256 + tx;
            int n = idx >> 2;
            int q = idx & 3;
            *(ushort8v*)&Bh[n * LSTR + q * 8] = whPre[buf][i];
            *(ushort8v*)&Bl[n * LSTR + q * 8] = wlPre[buf][i];
        }
        if (c < 3) loadChunk(kk + 32, buf ^ 1);  // prefetch next chunk
        __syncthreads();

        short8v ab[4], bh[2], bl[2];
#pragma unroll
        for (int t = 0; t < 4; ++t)
            ab[t] = *(const short8v*)&Ab[(t * 16 + mrow) * LSTR + quad * 8];
#pragma unroll
        for (int t = 0; t < 2; ++t) {
            bh[t] = *(const short8v*)&Bh[(cw + t * 16 + mrow) * LSTR + quad * 8];
            bl[t] = *(const short8v*)&Bl[(cw + t * 16 + mrow) * LSTR + quad * 8];
        }
#pragma unroll
        for (int ti = 0; ti < 4; ++ti)
#pragma unroll
            for (int tj = 0; tj < 2; ++tj) {
                acc[ti][tj] = __builtin_amdgcn_mfma_f32_16x16x32_bf16(ab[ti], bh[tj], acc[ti][tj], 0, 0, 0);
                acc[ti][tj] = __builtin_amdgcn_mfma_f32_16x16x32_bf16(ab[ti], bl[tj], acc[ti][tj], 0, 0, 0);
            }
    }

#pragma unroll
    for (int ti = 0; ti < 4; ++ti) {
#pragma unroll
        for (int i = 0; i < 4; ++i) {
            int gr = rowBase + ti * 16 + quad * 4 + i;
            if (gr < N) {
#pragma unroll
                for (int tj = 0; tj < 2; ++tj)
                    outB[(size_t)gr * H + cw + tj * 16 + mrow] = bf16h(acc[ti][tj][i]);
            }
        }
    }
}

// ---------------- CSR aggregation + fused BN partial-reduce ------------------
// 64 nodes/block: 4 waves x 16 sequential nodes. 8-wide gather batches,
// prescaled src byte-offsets. Each lane also accumulates sum/sumsq of its
// 2 channels; block-reduce -> partial[block][256] (no separate bn_reduce).
#define AGG_NPB 64
__global__ __launch_bounds__(256) void agg_kernel(const unsigned short* __restrict__ ht,
    const int* __restrict__ row_ptr, const float2* __restrict__ edge_data,
    const float* __restrict__ dis, const float* __restrict__ bias,
    unsigned short* __restrict__ C, float* __restrict__ partial, int N)
{
    int waveId = threadIdx.x >> 6;
    int lane = threadIdx.x & 63;
    int lane4 = lane * 4;  // byte offset of this lane's dword within a row
    float2 b = ((const float2*)bias)[lane];
    const char* htb = (const char*)ht;

    float sx = 0.f, sy = 0.f, qx = 0.f, qy = 0.f;

    int nodeBase = blockIdx.x * AGG_NPB + waveId * 16;
    for (int k = 0; k < 16; ++k) {
        int node = nodeBase + k;
        if (node >= N) break;
        int start = row_ptr[node], end = row_ptr[node + 1];
        int cnt = end - start;
        float d = dis[node];
        float n2 = d * d;
        unsigned int uv = *(const unsigned int*)(htb + ((size_t)node << 8) + lane4);
        float ax[4], ay[4];
        ax[0] = bf16f((unsigned short)(uv & 0xffffu)) * n2 + b.x;
        ay[0] = bf16f((unsigned short)(uv >> 16)) * n2 + b.y;
        ax[1] = 0.f; ay[1] = 0.f; ax[2] = 0.f; ay[2] = 0.f; ax[3] = 0.f; ay[3] = 0.f;

        int cmain = cnt > 64 ? 64 : cnt;
        float2 edl = (lane < cmain) ? edge_data[start + lane] : make_float2(0.f, 0.f);

        for (int j = 0; j < cmain; j += 8) {
            int s[8]; float w[8]; unsigned int u[8];
#pragma unroll
            for (int i = 0; i < 8; ++i) {
                s[i] = __float_as_int(__shfl(edl.x, j + i, 64));
                w[i] = __shfl(edl.y, j + i, 64);
            }
#pragma unroll
            for (int i = 0; i < 8; ++i)
                u[i] = *(const unsigned int*)(htb + (size_t)(unsigned int)(s[i] + lane4));
#pragma unroll
            for (int i = 0; i < 8; ++i) {
                ax[i & 3] += bf16f((unsigned short)(u[i] & 0xffffu)) * w[i];
                ay[i & 3] += bf16f((unsigned short)(u[i] >> 16)) * w[i];
            }
        }
        for (int e = start + 64; e < end; ++e) {  // rare: degree > 64
            float2 ed = edge_data[e];
            int si = __float_as_int(ed.x);
            unsigned int u0 = *(const unsigned int*)(htb + (size_t)(unsigned int)(si + lane4));
            ax[0] += bf16f((unsigned short)(u0 & 0xffffu)) * ed.y;
            ay[0] += bf16f((unsigned short)(u0 >> 16)) * ed.y;
        }
        float ox = (ax[0] + ax[1]) + (ax[2] + ax[3]);
        float oy = (ay[0] + ay[1]) + (ay[2] + ay[3]);
        unsigned int packed = ((unsigned int)bf16h(oy) << 16) | (unsigned int)bf16h(ox);
        *(unsigned int*)((char*)C + ((size_t)node << 8) + lane4) = packed;
        sx += ox; sy += oy;
        qx += ox * ox; qy += oy * oy;
    }

    __shared__ float4 red[4][64];
    red[waveId][lane] = make_float4(sx, sy, qx, qy);
    __syncthreads();
    int t = threadIdx.x;
    if (t < 128) {
        int l = t >> 1, comp = t & 1;
        float s = 0.f, q = 0.f;
#pragma unroll
        for (int wv = 0; wv < 4; ++wv) {
            float4 v = red[wv][l];
            s += comp ? v.y : v.x;
            q += comp ? v.w : v.z;
        }
        partial[(size_t)blockIdx.x * 256 + t] = s;
        partial[(size_t)blockIdx.x * 256 + 128 + t] = q;
    }
}

// ---------------- BN finalize: sum partials (nb rows) + scale/shift ----------
__global__ __launch_bounds__(1024) void bn_finalize_kernel(const float* __restrict__ partial,
    float* __restrict__ stats, const float* __restrict__ gamma,
    const float* __restrict__ beta, float invN, int nb)
{
    __shared__ float vals[4][256];
    int t = threadIdx.x;
    int c = t & 255;
    int slice = t >> 8;  // 0..3
    float s = 0.f;
#pragma unroll 4
    for (int b = slice; b < nb; b += 4)
        s += partial[(size_t)b * 256 + c];
    vals[slice][c] = s;
    __syncthreads();
    if (t < 256)
        vals[0][t] = vals[0][t] + vals[1][t] + vals[2][t] + vals[3][t];
    __syncthreads();
    if (t < 128) {
        float mean = vals[0][t] * invN;
        float var = vals[0][t + 128] * invN - mean * mean;
        float inv = rsqrtf(var + BN_EPS);
        float sc = gamma[t] * inv;
        stats[2 * H + t] = sc;
        stats[3 * H + t] = beta[t] - mean * sc;
    }
}

// ---------------- final-layer BN apply + residual (bf16 C, bf16 A, no relu) --
__global__ __launch_bounds__(256) void bn_apply_kernel(const unsigned short* __restrict__ C,
    const float* __restrict__ stats, unsigned short* __restrict__ A, int N)
{
    int i = blockIdx.x * 256 + threadIdx.x;
    int node = i >> 5;
    if (node >= N) return;
    int c4 = i & 31;
    uint2 u = ((const uint2*)C)[i];
    float4 sc = ((const float4*)(stats + 2 * H))[c4];
    float4 sh = ((const float4*)(stats + 3 * H))[c4];
    ushort4v a = *(const ushort4v*)&A[(size_t)node * H + c4 * 4];
    float ox = bf16f((unsigned short)(u.x & 0xffffu)) * sc.x + sh.x + bf16f(a[0]);
    float oy = bf16f((unsigned short)(u.x >> 16)) * sc.y + sh.y + bf16f(a[1]);
    float oz = bf16f((unsigned short)(u.y & 0xffffu)) * sc.z + sh.z + bf16f(a[2]);
    float ow = bf16f((unsigned short)(u.y >> 16)) * sc.w + sh.w + bf16f(a[3]);
    ushort4v o = {bf16h(ox), bf16h(oy), bf16h(oz), bf16h(ow)};
    *(ushort4v*)&A[(size_t)node * H + c4 * 4] = o;
}

// ---------------- mean-pool: segmented reduction over sorted batch_idx -------
#define POOL_ROWS 64
__global__ __launch_bounds__(128) void pool_kernel(const unsigned short* __restrict__ A,
    const int* __restrict__ batch, float* __restrict__ pooled,
    float* __restrict__ counts, int N)
{
    int c = threadIdx.x;
    int base = blockIdx.x * POOL_ROWS;
    int end = base + POOL_ROWS;
    if (end > N) end = N;
    if (base >= N) return;
    int curg = batch[base];
    int runStart = base;
    float acc = 0.f;
    for (int r = base; r < end; ++r) {
        int g = batch[r];
        if (g != curg) {
            atomicAdd(&pooled[(size_t)curg * H + c], acc);
            if (c == 0) atomicAdd(&counts[curg], (float)(r - runStart));
            curg = g;
            acc = 0.f;
            runStart = r;
        }
        acc += bf16f(A[(size_t)r * H + c]);
    }
    atomicAdd(&pooled[(size_t)curg * H + c], acc);
    if (c == 0) atomicAdd(&counts[curg], (float)(end - runStart));
}

// ---------------- final: sigmoid(mean . linW + b) ----------------------------
__global__ __launch_bounds__(256) void final_kernel(const float* __restrict__ pooled,
    const float* __restrict__ counts, const float* __restrict__ linW,
    const float* __restrict__ linb, float* __restrict__ out, int G)
{
    int g = blockIdx.x * 4 + (threadIdx.x >> 6);
    int lane = threadIdx.x & 63;
    if (g >= G) return;
    float2 p = ((const float2*)(pooled + (size_t)g * H))[lane];
    float2 w = ((const float2*)linW)[lane];
    float part = p.x * w.x + p.y * w.y;
#pragma unroll
    for (int off = 32; off > 0; off >>= 1)
        part += __shfl_down(part, off, 64);
    if (lane == 0) {
        float cnt = fmaxf(counts[g], 1.0f);
        float z = part / cnt + linb[0];
        out[g] = 1.0f / (1.0f + expf(-z));
    }
}

static inline size_t align4(size_t x) { return (x + 3) & ~(size_t)3; }  // 16B align (in floats)

extern "C" void kernel_launch(void* const* d_in, const int* in_sizes, int n_in,
                              void* d_out, int out_size, void* d_ws, size_t ws_size,
                              hipStream_t stream)
{
    const int* x = (const int*)d_in[0];
    const int* ei = (const int*)d_in[1];
    const int* batch = (const int*)d_in[2];
    const float* table = (const float*)d_in[3];
    const float* convW = (const float*)d_in[4];
    const float* convB = (const float*)d_in[5];
    const float* gamma = (const float*)d_in[6];
    const float* beta = (const float*)d_in[7];
    const float* linW = (const float*)d_in[8];
    const float* linb = (const float*)d_in[9];
    float* out = (float*)d_out;

    int N = in_sizes[0] / 9;
    int E = in_sizes[1] / 2;
    int G = out_size;
    int L = in_sizes[4] / (H * H);
    const int* row = ei;
    const int* col = ei + E;
    int NB = (N + 255) / 256;  // blocks for scan (must be <= 512)
    int aggBlocks = (N + AGG_NPB - 1) / AGG_NPB;

    float* ws = (float*)d_ws;
    size_t off = 0;
    // ---- zeroed region ----
    int* deg = (int*)(ws + off);        off = align4(off + N);
    int* cnt = (int*)(ws + off);        off = align4(off + N);
    float* pooled = ws + off;           off = align4(off + (size_t)G * H);
    float* counts = ws + off;           off = align4(off + G);
    float* stats = ws + off;            off = align4(off + (size_t)L * 4 * H);
    size_t zero_bytes = off * sizeof(float);
    // ---- non-zeroed ----
    float* dis = ws + off;              off = align4(off + N);
    int* row_ptr = (int*)(ws + off);    off = align4(off + N + 1);
    int* blockSums = (int*)(ws + off);  off = align4(off + 512);
    float* partial = ws + off;          off = align4(off + (size_t)aggBlocks * 256);
    unsigned short* wt = (unsigned short*)(ws + off); off = align4(off + (size_t)L * H * H);  // L*2*H*H ushort
    float2* edge_data = (float2*)(ws + off); off = align4(off + (size_t)2 * E);
    unsigned short* A = (unsigned short*)(ws + off); off = align4(off + (size_t)N * H / 2);  // bf16 h
    unsigned short* B = (unsigned short*)(ws + off); off = align4(off + (size_t)N * H / 2);  // bf16 ht
    unsigned short* C = (unsigned short*)(ws + off); off = align4(off + (size_t)N * H / 2);  // bf16 agg

    hipMemsetAsync(d_ws, 0, zero_bytes, stream);

    enc_kernel<<<(N * 32 + 255) / 256, 256, 0, stream>>>(x, table, A, N);
    deg_kernel<<<(E + 255) / 256, 256, 0, stream>>>(col, deg, E);
    dis_kernel<<<(N + 255) / 256, 256, 0, stream>>>(deg, dis, N);
    scan1_kernel<<<NB, 256, 0, stream>>>(deg, blockSums, N);
    scan2_kernel<<<1, 512, 0, stream>>>(blockSums, NB);
    scan3_kernel<<<NB, 256, 0, stream>>>(deg, blockSums, row_ptr, N, E);
    fill_kernel<<<(E + 255) / 256, 256, 0, stream>>>(row, col, row_ptr, cnt, dis, edge_data, E);
    wprep_kernel<<<L * 128, 128, 0, stream>>>(convW, wt, L);

    int gemmBlocks = (N + 63) / 64;
    for (int l = 0; l < L; ++l) {
        float* st = stats + (size_t)l * 4 * H;
        const float* stPrev = stats + (size_t)(l > 0 ? l - 1 : 0) * 4 * H;
        const unsigned short* wthi = wt + (size_t)l * 2 * H * H;
        gemm_mfma_kernel<<<gemmBlocks, 256, 0, stream>>>(A, C, stPrev, wthi, B, A, N,
                                                         l > 0 ? 1 : 0);
        agg_kernel<<<aggBlocks, 256, 0, stream>>>(B, row_ptr, edge_data, dis,
                                                  convB + (size_t)l * H, C, partial, N);
        bn_finalize_kernel<<<1, 1024, 0, stream>>>(partial, st, gamma + (size_t)l * H,
                                                   beta + (size_t)l * H, 1.0f / (float)N,
                                                   aggBlocks);
    }

    // final layer BN apply (no relu) + residual
    bn_apply_kernel<<<(N * 32 + 255) / 256, 256, 0, stream>>>(
        C, stats + (size_t)(L - 1) * 4 * H, A, N);

    pool_kernel<<<(N + POOL_ROWS - 1) / POOL_ROWS, 128, 0, stream>>>(A, batch, pooled, counts, N);
    final_kernel<<<(G + 3) / 4, 256, 0, stream>>>(pooled, counts, linW, linb, out, G);
}

// Round 15
// 616.496 us; speedup vs baseline: 1.1478x; 1.1478x over previous
//
#include <hip/hip_runtime.h>
#include <math.h>

#define H 128
#define BN_EPS 1e-5f

typedef float float4v __attribute__((ext_vector_type(4)));
typedef short short8v __attribute__((ext_vector_type(8)));
typedef unsigned short ushort4v __attribute__((ext_vector_type(4)));
typedef unsigned short ushort8v __attribute__((ext_vector_type(8)));

__device__ inline unsigned short bf16h(float x) {
    unsigned int u = __float_as_uint(x);
    return (unsigned short)((u + 0x7fffu + ((u >> 16) & 1u)) >> 16);
}
__device__ inline float bf16f(unsigned short h) {
    return __uint_as_float(((unsigned int)h) << 16);
}

// ---------------- Atom encoder: bf16 output h0 -------------------------------
__global__ __launch_bounds__(256) void enc_kernel(const int* __restrict__ x,
    const float* __restrict__ table, unsigned short* __restrict__ h, int N)
{
    int i = blockIdx.x * 256 + threadIdx.x;
    int node = i >> 5;
    if (node >= N) return;
    int c4 = i & 31;
    const int offs[9] = {0, 119, 123, 135, 147, 157, 163, 169, 171};
    const int* xr = x + node * 9;
    float4 s = make_float4(0.f, 0.f, 0.f, 0.f);
#pragma unroll
    for (int f = 0; f < 9; ++f) {
        float4 v = ((const float4*)(table + (size_t)(xr[f] + offs[f]) * H))[c4];
        s.x += v.x; s.y += v.y; s.z += v.z; s.w += v.w;
    }
    ushort4v o = {bf16h(s.x), bf16h(s.y), bf16h(s.z), bf16h(s.w)};
    *(ushort4v*)&h[(size_t)node * H + c4 * 4] = o;
}

// ---------------- degree (in-degree over col), int atomics -------------------
__global__ __launch_bounds__(256) void deg_kernel(const int* __restrict__ col,
                                                  int* __restrict__ deg, int E)
{
    int e = blockIdx.x * 256 + threadIdx.x;
    if (e < E) atomicAdd(&deg[col[e]], 1);
}

__global__ __launch_bounds__(256) void dis_kernel(const int* __restrict__ deg,
                                                  float* __restrict__ dis, int N)
{
    int i = blockIdx.x * 256 + threadIdx.x;
    if (i < N) dis[i] = rsqrtf((float)deg[i] + 1.0f);  // +1 = self loop
}

// ---------------- scan step 1: per-block sums of deg -------------------------
__global__ __launch_bounds__(256) void scan1_kernel(const int* __restrict__ deg,
    int* __restrict__ blockSums, int N)
{
    __shared__ int s[256];
    int t = threadIdx.x;
    int g = blockIdx.x * 256 + t;
    s[t] = (g < N) ? deg[g] : 0;
    __syncthreads();
#pragma unroll
    for (int off = 128; off > 0; off >>= 1) {
        if (t < off) s[t] += s[t + off];
        __syncthreads();
    }
    if (t == 0) blockSums[blockIdx.x] = s[0];
}

// ---------------- scan step 2: exclusive scan of block sums (<=512) ----------
__global__ __launch_bounds__(512) void scan2_kernel(int* __restrict__ blockSums, int NB)
{
    __shared__ int s[512];
    int t = threadIdx.x;
    int own = (t < NB) ? blockSums[t] : 0;
    s[t] = own;
    __syncthreads();
    for (int off = 1; off < 512; off <<= 1) {
        int v = (t >= off) ? s[t - off] : 0;
        __syncthreads();
        s[t] += v;
        __syncthreads();
    }
    if (t < NB) blockSums[t] = s[t] - own;  // exclusive
}

// ---------------- scan step 3: final row_ptr ---------------------------------
__global__ __launch_bounds__(256) void scan3_kernel(const int* __restrict__ deg,
    const int* __restrict__ blockOff, int* __restrict__ row_ptr, int N, int E)
{
    __shared__ int s[256];
    int t = threadIdx.x;
    int g = blockIdx.x * 256 + t;
    int own = (g < N) ? deg[g] : 0;
    s[t] = own;
    __syncthreads();
    for (int off = 1; off < 256; off <<= 1) {
        int v = (t >= off) ? s[t - off] : 0;
        __syncthreads();
        s[t] += v;
        __syncthreads();
    }
    if (g < N) row_ptr[g] = blockOff[blockIdx.x] + s[t] - own;
    if (g == N - 1) row_ptr[N] = E;
}

// ---------------- fill CSR: edge_data[pos] = {src_byte_offset, norm} ---------
__global__ __launch_bounds__(256) void fill_kernel(const int* __restrict__ row,
    const int* __restrict__ col, const int* __restrict__ row_ptr,
    int* __restrict__ cnt, const float* __restrict__ dis,
    float2* __restrict__ edge_data, int E)
{
    int e = blockIdx.x * 256 + threadIdx.x;
    if (e >= E) return;
    int r = row[e], c = col[e];
    int pos = row_ptr[c] + atomicAdd(&cnt[c], 1);
    // store src * 256 (byte offset of bf16 row of H=128) for cheap gather addressing
    edge_data[pos] = make_float2(__int_as_float(r << 8), dis[r] * dis[c]);
}

// ---------------- W prep: Wt_hi/lo[l][n][k] = bf16split(W[l][k][n]) ----------
__global__ __launch_bounds__(128) void wprep_kernel(const float* __restrict__ W,
    unsigned short* __restrict__ wt, int L)
{
    int b = blockIdx.x;
    int l = b >> 7, k = b & 127;
    int n = threadIdx.x;
    float x = W[(size_t)l * H * H + (size_t)k * H + n];
    unsigned short hi = bf16h(x);
    unsigned short lo = bf16h(x - bf16f(hi));
    unsigned short* base = wt + (size_t)l * 2 * H * H;
    base[(size_t)n * H + k] = hi;                       // hi block [n][k]
    base[(size_t)H * H + (size_t)n * H + k] = lo;       // lo block [n][k]
}

// ---------------- MFMA GEMM + fused prev-layer BN-apply, 64-row tile ---------
#define LSTR 40  // LDS row stride in shorts (padded from 32)
__global__ __launch_bounds__(256) void gemm_mfma_kernel(
    const unsigned short* __restrict__ Ain, const unsigned short* __restrict__ Cin,
    const float* __restrict__ stats, const unsigned short* __restrict__ wthi,
    unsigned short* __restrict__ outB, unsigned short* __restrict__ Aout,
    int N, int fuse)
{
    __shared__ unsigned short Ab[64 * LSTR];
    __shared__ unsigned short Bh[128 * LSTR];
    __shared__ unsigned short Bl[128 * LSTR];

    const unsigned short* wtlo = wthi + H * H;
    const int tx = threadIdx.x;
    const int rowBase = blockIdx.x * 64;
    const int lane = tx & 63;
    const int w = tx >> 6;
    const int cw = w * 32;           // 32-col strip per wave
    const int mrow = lane & 15;
    const int quad = lane >> 4;

    const float4* sc4 = (const float4*)(stats + 2 * H);
    const float4* sh4 = (const float4*)(stats + 3 * H);

    float4v acc[4][2];
#pragma unroll
    for (int i = 0; i < 4; ++i)
#pragma unroll
        for (int j = 0; j < 2; ++j)
            acc[i][j] = (float4v)(0.f);

    ushort4v aPre[2][2], cPre[2][2];
    ushort8v whPre[2][2], wlPre[2][2];

    auto loadChunk = [&](int kk, int buf) {
#pragma unroll
        for (int i = 0; i < 2; ++i) {
            int idx = i * 256 + tx;   // 0..511
            int r = idx >> 3;         // 0..63
            int f4 = idx & 7;
            int gr = rowBase + r;
            ushort4v av = {0, 0, 0, 0}, cv = {0, 0, 0, 0};
            if (gr < N) {
                av = *(const ushort4v*)&Ain[(size_t)gr * H + kk + f4 * 4];
                if (fuse) cv = *(const ushort4v*)&Cin[(size_t)gr * H + kk + f4 * 4];
            }
            aPre[buf][i] = av;
            cPre[buf][i] = cv;
        }
#pragma unroll
        for (int i = 0; i < 2; ++i) {
            int idx = i * 256 + tx;   // 0..511
            int n = idx >> 2;         // 0..127
            int q = idx & 3;
            whPre[buf][i] = *(const ushort8v*)&wthi[(size_t)n * H + kk + q * 8];
            wlPre[buf][i] = *(const ushort8v*)&wtlo[(size_t)n * H + kk + q * 8];
        }
    };

    loadChunk(0, 0);

#pragma unroll
    for (int c = 0; c < 4; ++c) {
        const int kk = c * 32;
        const int buf = c & 1;
        __syncthreads();
#pragma unroll
        for (int i = 0; i < 2; ++i) {
            int idx = i * 256 + tx;
            int r = idx >> 3;
            int f4 = idx & 7;
            int gr = rowBase + r;
            ushort4v hv = aPre[buf][i];
            if (fuse) {
                int cq = (kk >> 2) + f4;
                float4 sc = sc4[cq];
                float4 sh = sh4[cq];
                ushort4v cv = cPre[buf][i];
                float ox = fmaxf(bf16f(cv[0]) * sc.x + sh.x, 0.f) + bf16f(hv[0]);
                float oy = fmaxf(bf16f(cv[1]) * sc.y + sh.y, 0.f) + bf16f(hv[1]);
                float oz = fmaxf(bf16f(cv[2]) * sc.z + sh.z, 0.f) + bf16f(hv[2]);
                float ow = fmaxf(bf16f(cv[3]) * sc.w + sh.w, 0.f) + bf16f(hv[3]);
                hv[0] = bf16h(ox); hv[1] = bf16h(oy);
                hv[2] = bf16h(oz); hv[3] = bf16h(ow);
                if (gr < N)
                    *(ushort4v*)&Aout[(size_t)gr * H + kk + f4 * 4] = hv;
            }
            *(ushort4v*)&Ab[r * LSTR + f4 * 4] = hv;
        }
#pragma unroll
        for (int i = 0; i < 2; ++i) {
            int idx = i * 256 + tx;
            int n = idx >> 2;
            int q = idx & 3;
            *(ushort8v*)&Bh[n * LSTR + q * 8] = whPre[buf][i];
            *(ushort8v*)&Bl[n * LSTR + q * 8] = wlPre[buf][i];
        }
        if (c < 3) loadChunk(kk + 32, buf ^ 1);  // prefetch next chunk
        __syncthreads();

        short8v ab[4], bh[2], bl[2];
#pragma unroll
        for (int t = 0; t < 4; ++t)
            ab[t] = *(const short8v*)&Ab[(t * 16 + mrow) * LSTR + quad * 8];
#pragma unroll
        for (int t = 0; t < 2; ++t) {
            bh[t] = *(const short8v*)&Bh[(cw + t * 16 + mrow) * LSTR + quad * 8];
            bl[t] = *(const short8v*)&Bl[(cw + t * 16 + mrow) * LSTR + quad * 8];
        }
#pragma unroll
        for (int ti = 0; ti < 4; ++ti)
#pragma unroll
            for (int tj = 0; tj < 2; ++tj) {
                acc[ti][tj] = __builtin_amdgcn_mfma_f32_16x16x32_bf16(ab[ti], bh[tj], acc[ti][tj], 0, 0, 0);
                acc[ti][tj] = __builtin_amdgcn_mfma_f32_16x16x32_bf16(ab[ti], bl[tj], acc[ti][tj], 0, 0, 0);
            }
    }

#pragma unroll
    for (int ti = 0; ti < 4; ++ti) {
#pragma unroll
        for (int i = 0; i < 4; ++i) {
            int gr = rowBase + ti * 16 + quad * 4 + i;
            if (gr < N) {
#pragma unroll
                for (int tj = 0; tj < 2; ++tj)
                    outB[(size_t)gr * H + cw + tj * 16 + mrow] = bf16h(acc[ti][tj][i]);
            }
        }
    }
}

// ---------------- CSR aggregation: one wave per node, 8-wide batches ---------
// prescaled src byte-offsets from fill; bf16 C out.
__global__ __launch_bounds__(256) void agg_kernel(const unsigned short* __restrict__ ht,
    const int* __restrict__ row_ptr, const float2* __restrict__ edge_data,
    const float* __restrict__ dis, const float* __restrict__ bias,
    unsigned short* __restrict__ C, int N)
{
    int wave = blockIdx.x * 4 + (threadIdx.x >> 6);
    int lane = threadIdx.x & 63;
    if (wave >= N) return;
    int lane4 = lane * 4;
    const char* htb = (const char*)ht;
    int start = row_ptr[wave], end = row_ptr[wave + 1];
    int cnt = end - start;
    float d = dis[wave];
    float n2 = d * d;
    unsigned int uv = *(const unsigned int*)(htb + ((size_t)wave << 8) + lane4);
    float2 b = ((const float2*)bias)[lane];
    float ax[4], ay[4];
    ax[0] = bf16f((unsigned short)(uv & 0xffffu)) * n2 + b.x;
    ay[0] = bf16f((unsigned short)(uv >> 16)) * n2 + b.y;
    ax[1] = 0.f; ay[1] = 0.f; ax[2] = 0.f; ay[2] = 0.f; ax[3] = 0.f; ay[3] = 0.f;

    int cmain = cnt > 64 ? 64 : cnt;
    // padding lanes get {src=0, w=0}: gather row 0 (L1-hot), contribute 0
    float2 edl = (lane < cmain) ? edge_data[start + lane] : make_float2(0.f, 0.f);

    for (int j = 0; j < cmain; j += 8) {
        int s[8]; float w[8]; unsigned int u[8];
#pragma unroll
        for (int i = 0; i < 8; ++i) {
            s[i] = __float_as_int(__shfl(edl.x, j + i, 64));
            w[i] = __shfl(edl.y, j + i, 64);
        }
#pragma unroll
        for (int i = 0; i < 8; ++i)
            u[i] = *(const unsigned int*)(htb + (size_t)(unsigned int)(s[i] + lane4));
#pragma unroll
        for (int i = 0; i < 8; ++i) {
            ax[i & 3] += bf16f((unsigned short)(u[i] & 0xffffu)) * w[i];
            ay[i & 3] += bf16f((unsigned short)(u[i] >> 16)) * w[i];
        }
    }
    for (int e = start + 64; e < end; ++e) {  // rare: degree > 64
        float2 ed = edge_data[e];
        int si = __float_as_int(ed.x);
        unsigned int u0 = *(const unsigned int*)(htb + (size_t)(unsigned int)(si + lane4));
        ax[0] += bf16f((unsigned short)(u0 & 0xffffu)) * ed.y;
        ay[0] += bf16f((unsigned short)(u0 >> 16)) * ed.y;
    }
    float ox = (ax[0] + ax[1]) + (ax[2] + ax[3]);
    float oy = (ay[0] + ay[1]) + (ay[2] + ay[3]);
    unsigned int packed = ((unsigned int)bf16h(oy) << 16) | (unsigned int)bf16h(ox);
    *(unsigned int*)((char*)C + ((size_t)wave << 8) + lane4) = packed;
}

// ---------------- BN reduce stage 1 (bf16 C): per-block partials -------------
#define BNR_GRID 512
__global__ __launch_bounds__(256) void bn_reduce_kernel(const unsigned short* __restrict__ C,
    float* __restrict__ partial, int N)
{
    __shared__ float4 ls[8][32];
    __shared__ float4 lq[8][32];
    int t = threadIdx.x;
    int c4 = t & 31, rg = t >> 5;
    float4 s = make_float4(0.f, 0.f, 0.f, 0.f);
    float4 q = make_float4(0.f, 0.f, 0.f, 0.f);
    const uint2* C2 = (const uint2*)C;
    for (int r = blockIdx.x * 8 + rg; r < N; r += BNR_GRID * 8) {
        uint2 u = C2[(size_t)r * 32 + c4];
        float vx = bf16f((unsigned short)(u.x & 0xffffu));
        float vy = bf16f((unsigned short)(u.x >> 16));
        float vz = bf16f((unsigned short)(u.y & 0xffffu));
        float vw = bf16f((unsigned short)(u.y >> 16));
        s.x += vx; s.y += vy; s.z += vz; s.w += vw;
        q.x += vx * vx; q.y += vy * vy; q.z += vz * vz; q.w += vw * vw;
    }
    ls[rg][c4] = s;
    lq[rg][c4] = q;
    __syncthreads();
    if (rg == 0) {
#pragma unroll
        for (int i = 1; i < 8; ++i) {
            float4 a = ls[i][c4];
            s.x += a.x; s.y += a.y; s.z += a.z; s.w += a.w;
            float4 b = lq[i][c4];
            q.x += b.x; q.y += b.y; q.z += b.z; q.w += b.w;
        }
        float4* p4 = (float4*)(partial + (size_t)blockIdx.x * 256);
        p4[c4] = s;
        p4[c4 + 32] = q;
    }
}

// ---------------- BN stage 2 + finalize: one block, 1024 threads -------------
__global__ __launch_bounds__(1024) void bn_finalize_kernel(const float* __restrict__ partial,
    float* __restrict__ stats, const float* __restrict__ gamma,
    const float* __restrict__ beta, float invN)
{
    __shared__ float vals[4][256];
    int t = threadIdx.x;
    int c = t & 255;
    int slice = t >> 8;  // 0..3
    float s = 0.f;
#pragma unroll 8
    for (int b = slice * (BNR_GRID / 4); b < (slice + 1) * (BNR_GRID / 4); ++b)
        s += partial[(size_t)b * 256 + c];
    vals[slice][c] = s;
    __syncthreads();
    if (t < 256)
        vals[0][t] = vals[0][t] + vals[1][t] + vals[2][t] + vals[3][t];
    __syncthreads();
    if (t < 128) {
        float mean = vals[0][t] * invN;
        float var = vals[0][t + 128] * invN - mean * mean;
        float inv = rsqrtf(var + BN_EPS);
        float sc = gamma[t] * inv;
        stats[2 * H + t] = sc;
        stats[3 * H + t] = beta[t] - mean * sc;
    }
}

// ---------------- final-layer BN apply + residual (bf16 C, bf16 A, no relu) --
__global__ __launch_bounds__(256) void bn_apply_kernel(const unsigned short* __restrict__ C,
    const float* __restrict__ stats, unsigned short* __restrict__ A, int N)
{
    int i = blockIdx.x * 256 + threadIdx.x;
    int node = i >> 5;
    if (node >= N) return;
    int c4 = i & 31;
    uint2 u = ((const uint2*)C)[i];
    float4 sc = ((const float4*)(stats + 2 * H))[c4];
    float4 sh = ((const float4*)(stats + 3 * H))[c4];
    ushort4v a = *(const ushort4v*)&A[(size_t)node * H + c4 * 4];
    float ox = bf16f((unsigned short)(u.x & 0xffffu)) * sc.x + sh.x + bf16f(a[0]);
    float oy = bf16f((unsigned short)(u.x >> 16)) * sc.y + sh.y + bf16f(a[1]);
    float oz = bf16f((unsigned short)(u.y & 0xffffu)) * sc.z + sh.z + bf16f(a[2]);
    float ow = bf16f((unsigned short)(u.y >> 16)) * sc.w + sh.w + bf16f(a[3]);
    ushort4v o = {bf16h(ox), bf16h(oy), bf16h(oz), bf16h(ow)};
    *(ushort4v*)&A[(size_t)node * H + c4 * 4] = o;
}

// ---------------- mean-pool: segmented reduction over sorted batch_idx -------
#define POOL_ROWS 64
__global__ __launch_bounds__(128) void pool_kernel(const unsigned short* __restrict__ A,
    const int* __restrict__ batch, float* __restrict__ pooled,
    float* __restrict__ counts, int N)
{
    int c = threadIdx.x;
    int base = blockIdx.x * POOL_ROWS;
    int end = base + POOL_ROWS;
    if (end > N) end = N;
    if (base >= N) return;
    int curg = batch[base];
    int runStart = base;
    float acc = 0.f;
    for (int r = base; r < end; ++r) {
        int g = batch[r];
        if (g != curg) {
            atomicAdd(&pooled[(size_t)curg * H + c], acc);
            if (c == 0) atomicAdd(&counts[curg], (float)(r - runStart));
            curg = g;
            acc = 0.f;
            runStart = r;
        }
        acc += bf16f(A[(size_t)r * H + c]);
    }
    atomicAdd(&pooled[(size_t)curg * H + c], acc);
    if (c == 0) atomicAdd(&counts[curg], (float)(end - runStart));
}

// ---------------- final: sigmoid(mean . linW + b) ----------------------------
__global__ __launch_bounds__(256) void final_kernel(const float* __restrict__ pooled,
    const float* __restrict__ counts, const float* __restrict__ linW,
    const float* __restrict__ linb, float* __restrict__ out, int G)
{
    int g = blockIdx.x * 4 + (threadIdx.x >> 6);
    int lane = threadIdx.x & 63;
    if (g >= G) return;
    float2 p = ((const float2*)(pooled + (size_t)g * H))[lane];
    float2 w = ((const float2*)linW)[lane];
    float part = p.x * w.x + p.y * w.y;
#pragma unroll
    for (int off = 32; off > 0; off >>= 1)
        part += __shfl_down(part, off, 64);
    if (lane == 0) {
        float cnt = fmaxf(counts[g], 1.0f);
        float z = part / cnt + linb[0];
        out[g] = 1.0f / (1.0f + expf(-z));
    }
}

static inline size_t align4(size_t x) { return (x + 3) & ~(size_t)3; }  // 16B align (in floats)

extern "C" void kernel_launch(void* const* d_in, const int* in_sizes, int n_in,
                              void* d_out, int out_size, void* d_ws, size_t ws_size,
                              hipStream_t stream)
{
    const int* x = (const int*)d_in[0];
    const int* ei = (const int*)d_in[1];
    const int* batch = (const int*)d_in[2];
    const float* table = (const float*)d_in[3];
    const float* convW = (const float*)d_in[4];
    const float* convB = (const float*)d_in[5];
    const float* gamma = (const float*)d_in[6];
    const float* beta = (const float*)d_in[7];
    const float* linW = (const float*)d_in[8];
    const float* linb = (const float*)d_in[9];
    float* out = (float*)d_out;

    int N = in_sizes[0] / 9;
    int E = in_sizes[1] / 2;
    int G = out_size;
    int L = in_sizes[4] / (H * H);
    const int* row = ei;
    const int* col = ei + E;
    int NB = (N + 255) / 256;  // blocks for scan (must be <= 512)

    float* ws = (float*)d_ws;
    size_t off = 0;
    // ---- zeroed region ----
    int* deg = (int*)(ws + off);        off = align4(off + N);
    int* cnt = (int*)(ws + off);        off = align4(off + N);
    float* pooled = ws + off;           off = align4(off + (size_t)G * H);
    float* counts = ws + off;           off = align4(off + G);
    float* stats = ws + off;            off = align4(off + (size_t)L * 4 * H);
    size_t zero_bytes = off * sizeof(float);
    // ---- non-zeroed ----
    float* dis = ws + off;              off = align4(off + N);
    int* row_ptr = (int*)(ws + off);    off = align4(off + N + 1);
    int* blockSums = (int*)(ws + off);  off = align4(off + 512);
    float* partial = ws + off;          off = align4(off + (size_t)BNR_GRID * 256);
    unsigned short* wt = (unsigned short*)(ws + off); off = align4(off + (size_t)L * H * H);  // L*2*H*H ushort
    float2* edge_data = (float2*)(ws + off); off = align4(off + (size_t)2 * E);
    unsigned short* A = (unsigned short*)(ws + off); off = align4(off + (size_t)N * H / 2);  // bf16 h
    unsigned short* B = (unsigned short*)(ws + off); off = align4(off + (size_t)N * H / 2);  // bf16 ht
    unsigned short* C = (unsigned short*)(ws + off); off = align4(off + (size_t)N * H / 2);  // bf16 agg

    hipMemsetAsync(d_ws, 0, zero_bytes, stream);

    enc_kernel<<<(N * 32 + 255) / 256, 256, 0, stream>>>(x, table, A, N);
    deg_kernel<<<(E + 255) / 256, 256, 0, stream>>>(col, deg, E);
    dis_kernel<<<(N + 255) / 256, 256, 0, stream>>>(deg, dis, N);
    scan1_kernel<<<NB, 256, 0, stream>>>(deg, blockSums, N);
    scan2_kernel<<<1, 512, 0, stream>>>(blockSums, NB);
    scan3_kernel<<<NB, 256, 0, stream>>>(deg, blockSums, row_ptr, N, E);
    fill_kernel<<<(E + 255) / 256, 256, 0, stream>>>(row, col, row_ptr, cnt, dis, edge_data, E);
    wprep_kernel<<<L * 128, 128, 0, stream>>>(convW, wt, L);

    int gemmBlocks = (N + 63) / 64;
    for (int l = 0; l < L; ++l) {
        float* st = stats + (size_t)l * 4 * H;
        const float* stPrev = stats + (size_t)(l > 0 ? l - 1 : 0) * 4 * H;
        const unsigned short* wthi = wt + (size_t)l * 2 * H * H;
        gemm_mfma_kernel<<<gemmBlocks, 256, 0, stream>>>(A, C, stPrev, wthi, B, A, N,
                                                         l > 0 ? 1 : 0);
        agg_kernel<<<(N + 3) / 4, 256, 0, stream>>>(B, row_ptr, edge_data, dis,
                                                    convB + (size_t)l * H, C, N);
        bn_reduce_kernel<<<BNR_GRID, 256, 0, stream>>>(C, partial, N);
        bn_finalize_kernel<<<1, 1024, 0, stream>>>(partial, st, gamma + (size_t)l * H,
                                                   beta + (size_t)l * H, 1.0f / (float)N);
    }

    // final layer BN apply (no relu) + residual
    bn_apply_kernel<<<(N * 32 + 255) / 256, 256, 0, stream>>>(
        C, stats + (size_t)(L - 1) * 4 * H, A, N);

    pool_kernel<<<(N + POOL_ROWS - 1) / POOL_ROWS, 128, 0, stream>>>(A, batch, pooled, counts, N);
    final_kernel<<<(G + 3) / 4, 256, 0, stream>>>(pooled, counts, linW, linb, out, G);
}

// Round 16
// 600.605 us; speedup vs baseline: 1.1782x; 1.0265x over previous
//
#include <hip/hip_runtime.h>
#include <math.h>

#define H 128
#define BN_EPS 1e-5f

typedef float float4v __attribute__((ext_vector_type(4)));
typedef short short8v __attribute__((ext_vector_type(8)));
typedef unsigned short ushort4v __attribute__((ext_vector_type(4)));
typedef unsigned short ushort8v __attribute__((ext_vector_type(8)));

__device__ inline unsigned short bf16h(float x) {
    unsigned int u = __float_as_uint(x);
    return (unsigned short)((u + 0x7fffu + ((u >> 16) & 1u)) >> 16);
}
__device__ inline float bf16f(unsigned short h) {
    return __uint_as_float(((unsigned int)h) << 16);
}

// ---------------- Atom encoder: bf16 output h0 -------------------------------
__global__ __launch_bounds__(256) void enc_kernel(const int* __restrict__ x,
    const float* __restrict__ table, unsigned short* __restrict__ h, int N)
{
    int i = blockIdx.x * 256 + threadIdx.x;
    int node = i >> 5;
    if (node >= N) return;
    int c4 = i & 31;
    const int offs[9] = {0, 119, 123, 135, 147, 157, 163, 169, 171};
    const int* xr = x + node * 9;
    float4 s = make_float4(0.f, 0.f, 0.f, 0.f);
#pragma unroll
    for (int f = 0; f < 9; ++f) {
        float4 v = ((const float4*)(table + (size_t)(xr[f] + offs[f]) * H))[c4];
        s.x += v.x; s.y += v.y; s.z += v.z; s.w += v.w;
    }
    ushort4v o = {bf16h(s.x), bf16h(s.y), bf16h(s.z), bf16h(s.w)};
    *(ushort4v*)&h[(size_t)node * H + c4 * 4] = o;
}

// ---------------- degree (in-degree over col), int atomics -------------------
__global__ __launch_bounds__(256) void deg_kernel(const int* __restrict__ col,
                                                  int* __restrict__ deg, int E)
{
    int e = blockIdx.x * 256 + threadIdx.x;
    if (e < E) atomicAdd(&deg[col[e]], 1);
}

// ---------------- scan step 1: per-block sums of deg -------------------------
__global__ __launch_bounds__(256) void scan1_kernel(const int* __restrict__ deg,
    int* __restrict__ blockSums, int N)
{
    __shared__ int s[256];
    int t = threadIdx.x;
    int g = blockIdx.x * 256 + t;
    s[t] = (g < N) ? deg[g] : 0;
    __syncthreads();
#pragma unroll
    for (int off = 128; off > 0; off >>= 1) {
        if (t < off) s[t] += s[t + off];
        __syncthreads();
    }
    if (t == 0) blockSums[blockIdx.x] = s[0];
}

// ---------------- scan step 2: exclusive scan of block sums (<=512) ----------
__global__ __launch_bounds__(512) void scan2_kernel(int* __restrict__ blockSums, int NB)
{
    __shared__ int s[512];
    int t = threadIdx.x;
    int own = (t < NB) ? blockSums[t] : 0;
    s[t] = own;
    __syncthreads();
    for (int off = 1; off < 512; off <<= 1) {
        int v = (t >= off) ? s[t - off] : 0;
        __syncthreads();
        s[t] += v;
        __syncthreads();
    }
    if (t < NB) blockSums[t] = s[t] - own;  // exclusive
}

// ---------------- scan step 3: final row_ptr + dis ---------------------------
__global__ __launch_bounds__(256) void scan3_kernel(const int* __restrict__ deg,
    const int* __restrict__ blockOff, int* __restrict__ row_ptr,
    float* __restrict__ dis, int N, int E)
{
    __shared__ int s[256];
    int t = threadIdx.x;
    int g = blockIdx.x * 256 + t;
    int own = (g < N) ? deg[g] : 0;
    s[t] = own;
    __syncthreads();
    for (int off = 1; off < 256; off <<= 1) {
        int v = (t >= off) ? s[t - off] : 0;
        __syncthreads();
        s[t] += v;
        __syncthreads();
    }
    if (g < N) {
        row_ptr[g] = blockOff[blockIdx.x] + s[t] - own;
        dis[g] = rsqrtf((float)own + 1.0f);  // +1 = self loop
    }
    if (g == N - 1) row_ptr[N] = E;
}

// ---------------- fill CSR: edge_data[pos] = {src_byte_offset, norm} ---------
__global__ __launch_bounds__(256) void fill_kernel(const int* __restrict__ row,
    const int* __restrict__ col, const int* __restrict__ row_ptr,
    int* __restrict__ cnt, const float* __restrict__ dis,
    float2* __restrict__ edge_data, int E)
{
    int e = blockIdx.x * 256 + threadIdx.x;
    if (e >= E) return;
    int r = row[e], c = col[e];
    int pos = row_ptr[c] + atomicAdd(&cnt[c], 1);
    // store src * 256 (byte offset of bf16 row of H=128) for cheap gather addressing
    edge_data[pos] = make_float2(__int_as_float(r << 8), dis[r] * dis[c]);
}

// ---------------- W prep: Wt_hi/lo[l][n][k] = bf16split(W[l][k][n]) ----------
__global__ __launch_bounds__(128) void wprep_kernel(const float* __restrict__ W,
    unsigned short* __restrict__ wt, int L)
{
    int b = blockIdx.x;
    int l = b >> 7, k = b & 127;
    int n = threadIdx.x;
    float x = W[(size_t)l * H * H + (size_t)k * H + n];
    unsigned short hi = bf16h(x);
    unsigned short lo = bf16h(x - bf16f(hi));
    unsigned short* base = wt + (size_t)l * 2 * H * H;
    base[(size_t)n * H + k] = hi;                       // hi block [n][k]
    base[(size_t)H * H + (size_t)n * H + k] = lo;       // lo block [n][k]
}

// ---------------- MFMA GEMM + fused prev-layer BN-apply, 64-row tile ---------
#define LSTR 40  // LDS row stride in shorts (padded from 32)
__global__ __launch_bounds__(256) void gemm_mfma_kernel(
    const unsigned short* __restrict__ Ain, const unsigned short* __restrict__ Cin,
    const float* __restrict__ stats, const unsigned short* __restrict__ wthi,
    unsigned short* __restrict__ outB, unsigned short* __restrict__ Aout,
    int N, int fuse)
{
    __shared__ unsigned short Ab[64 * LSTR];
    __shared__ unsigned short Bh[128 * LSTR];
    __shared__ unsigned short Bl[128 * LSTR];

    const unsigned short* wtlo = wthi + H * H;
    const int tx = threadIdx.x;
    const int rowBase = blockIdx.x * 64;
    const int lane = tx & 63;
    const int w = tx >> 6;
    const int cw = w * 32;           // 32-col strip per wave
    const int mrow = lane & 15;
    const int quad = lane >> 4;

    const float4* sc4 = (const float4*)(stats + 2 * H);
    const float4* sh4 = (const float4*)(stats + 3 * H);

    float4v acc[4][2];
#pragma unroll
    for (int i = 0; i < 4; ++i)
#pragma unroll
        for (int j = 0; j < 2; ++j)
            acc[i][j] = (float4v)(0.f);

    ushort4v aPre[2][2], cPre[2][2];
    ushort8v whPre[2][2], wlPre[2][2];

    auto loadChunk = [&](int kk, int buf) {
#pragma unroll
        for (int i = 0; i < 2; ++i) {
            int idx = i * 256 + tx;   // 0..511
            int r = idx >> 3;         // 0..63
            int f4 = idx & 7;
            int gr = rowBase + r;
            ushort4v av = {0, 0, 0, 0}, cv = {0, 0, 0, 0};
            if (gr < N) {
                av = *(const ushort4v*)&Ain[(size_t)gr * H + kk + f4 * 4];
                if (fuse) cv = *(const ushort4v*)&Cin[(size_t)gr * H + kk + f4 * 4];
            }
            aPre[buf][i] = av;
            cPre[buf][i] = cv;
        }
#pragma unroll
        for (int i = 0; i < 2; ++i) {
            int idx = i * 256 + tx;   // 0..511
            int n = idx >> 2;         // 0..127
            int q = idx & 3;
            whPre[buf][i] = *(const ushort8v*)&wthi[(size_t)n * H + kk + q * 8];
            wlPre[buf][i] = *(const ushort8v*)&wtlo[(size_t)n * H + kk + q * 8];
        }
    };

    loadChunk(0, 0);

#pragma unroll
    for (int c = 0; c < 4; ++c) {
        const int kk = c * 32;
        const int buf = c & 1;
        __syncthreads();
#pragma unroll
        for (int i = 0; i < 2; ++i) {
            int idx = i * 256 + tx;
            int r = idx >> 3;
            int f4 = idx & 7;
            int gr = rowBase + r;
            ushort4v hv = aPre[buf][i];
            if (fuse) {
                int cq = (kk >> 2) + f4;
                float4 sc = sc4[cq];
                float4 sh = sh4[cq];
                ushort4v cv = cPre[buf][i];
                float ox = fmaxf(bf16f(cv[0]) * sc.x + sh.x, 0.f) + bf16f(hv[0]);
                float oy = fmaxf(bf16f(cv[1]) * sc.y + sh.y, 0.f) + bf16f(hv[1]);
                float oz = fmaxf(bf16f(cv[2]) * sc.z + sh.z, 0.f) + bf16f(hv[2]);
                float ow = fmaxf(bf16f(cv[3]) * sc.w + sh.w, 0.f) + bf16f(hv[3]);
                hv[0] = bf16h(ox); hv[1] = bf16h(oy);
                hv[2] = bf16h(oz); hv[3] = bf16h(ow);
                if (gr < N)
                    *(ushort4v*)&Aout[(size_t)gr * H + kk + f4 * 4] = hv;
            }
            *(ushort4v*)&Ab[r * LSTR + f4 * 4] = hv;
        }
#pragma unroll
        for (int i = 0; i < 2; ++i) {
            int idx = i * 256 + tx;
            int n = idx >> 2;
            int q = idx & 3;
            *(ushort8v*)&Bh[n * LSTR + q * 8] = whPre[buf][i];
            *(ushort8v*)&Bl[n * LSTR + q * 8] = wlPre[buf][i];
        }
        if (c < 3) loadChunk(kk + 32, buf ^ 1);  // prefetch next chunk
        __syncthreads();

        short8v ab[4], bh[2], bl[2];
#pragma unroll
        for (int t = 0; t < 4; ++t)
            ab[t] = *(const short8v*)&Ab[(t * 16 + mrow) * LSTR + quad * 8];
#pragma unroll
        for (int t = 0; t < 2; ++t) {
            bh[t] = *(const short8v*)&Bh[(cw + t * 16 + mrow) * LSTR + quad * 8];
            bl[t] = *(const short8v*)&Bl[(cw + t * 16 + mrow) * LSTR + quad * 8];
        }
#pragma unroll
        for (int ti = 0; ti < 4; ++ti)
#pragma unroll
            for (int tj = 0; tj < 2; ++tj) {
                acc[ti][tj] = __builtin_amdgcn_mfma_f32_16x16x32_bf16(ab[ti], bh[tj], acc[ti][tj], 0, 0, 0);
                acc[ti][tj] = __builtin_amdgcn_mfma_f32_16x16x32_bf16(ab[ti], bl[tj], acc[ti][tj], 0, 0, 0);
            }
    }

#pragma unroll
    for (int ti = 0; ti < 4; ++ti) {
#pragma unroll
        for (int i = 0; i < 4; ++i) {
            int gr = rowBase + ti * 16 + quad * 4 + i;
            if (gr < N) {
#pragma unroll
                for (int tj = 0; tj < 2; ++tj)
                    outB[(size_t)gr * H + cw + tj * 16 + mrow] = bf16h(acc[ti][tj][i]);
            }
        }
    }
}

// ---------------- CSR aggregation: one wave per node, 8-wide batches ---------
// prescaled src byte-offsets from fill; bf16 C out.
__global__ __launch_bounds__(256) void agg_kernel(const unsigned short* __restrict__ ht,
    const int* __restrict__ row_ptr, const float2* __restrict__ edge_data,
    const float* __restrict__ dis, const float* __restrict__ bias,
    unsigned short* __restrict__ C, int N)
{
    int wave = blockIdx.x * 4 + (threadIdx.x >> 6);
    int lane = threadIdx.x & 63;
    if (wave >= N) return;
    int lane4 = lane * 4;
    const char* htb = (const char*)ht;
    int start = row_ptr[wave], end = row_ptr[wave + 1];
    int cnt = end - start;
    float d = dis[wave];
    float n2 = d * d;
    unsigned int uv = *(const unsigned int*)(htb + ((size_t)wave << 8) + lane4);
    float2 b = ((const float2*)bias)[lane];
    float ax[4], ay[4];
    ax[0] = bf16f((unsigned short)(uv & 0xffffu)) * n2 + b.x;
    ay[0] = bf16f((unsigned short)(uv >> 16)) * n2 + b.y;
    ax[1] = 0.f; ay[1] = 0.f; ax[2] = 0.f; ay[2] = 0.f; ax[3] = 0.f; ay[3] = 0.f;

    int cmain = cnt > 64 ? 64 : cnt;
    // padding lanes get {src=0, w=0}: gather row 0 (L1-hot), contribute 0
    float2 edl = (lane < cmain) ? edge_data[start + lane] : make_float2(0.f, 0.f);

    for (int j = 0; j < cmain; j += 8) {
        int s[8]; float w[8]; unsigned int u[8];
#pragma unroll
        for (int i = 0; i < 8; ++i) {
            s[i] = __float_as_int(__shfl(edl.x, j + i, 64));
            w[i] = __shfl(edl.y, j + i, 64);
        }
#pragma unroll
        for (int i = 0; i < 8; ++i)
            u[i] = *(const unsigned int*)(htb + (size_t)(unsigned int)(s[i] + lane4));
#pragma unroll
        for (int i = 0; i < 8; ++i) {
            ax[i & 3] += bf16f((unsigned short)(u[i] & 0xffffu)) * w[i];
            ay[i & 3] += bf16f((unsigned short)(u[i] >> 16)) * w[i];
        }
    }
    for (int e = start + 64; e < end; ++e) {  // rare: degree > 64
        float2 ed = edge_data[e];
        int si = __float_as_int(ed.x);
        unsigned int u0 = *(const unsigned int*)(htb + (size_t)(unsigned int)(si + lane4));
        ax[0] += bf16f((unsigned short)(u0 & 0xffffu)) * ed.y;
        ay[0] += bf16f((unsigned short)(u0 >> 16)) * ed.y;
    }
    float ox = (ax[0] + ax[1]) + (ax[2] + ax[3]);
    float oy = (ay[0] + ay[1]) + (ay[2] + ay[3]);
    unsigned int packed = ((unsigned int)bf16h(oy) << 16) | (unsigned int)bf16h(ox);
    *(unsigned int*)((char*)C + ((size_t)wave << 8) + lane4) = packed;
}

// ---------------- BN reduce stage 1 (bf16 C): per-block partials -------------
#define BNR_GRID 512
__global__ __launch_bounds__(256) void bn_reduce_kernel(const unsigned short* __restrict__ C,
    float* __restrict__ partial, int N)
{
    __shared__ float4 ls[8][32];
    __shared__ float4 lq[8][32];
    int t = threadIdx.x;
    int c4 = t & 31, rg = t >> 5;
    float4 s = make_float4(0.f, 0.f, 0.f, 0.f);
    float4 q = make_float4(0.f, 0.f, 0.f, 0.f);
    const uint2* C2 = (const uint2*)C;
    for (int r = blockIdx.x * 8 + rg; r < N; r += BNR_GRID * 8) {
        uint2 u = C2[(size_t)r * 32 + c4];
        float vx = bf16f((unsigned short)(u.x & 0xffffu));
        float vy = bf16f((unsigned short)(u.x >> 16));
        float vz = bf16f((unsigned short)(u.y & 0xffffu));
        float vw = bf16f((unsigned short)(u.y >> 16));
        s.x += vx; s.y += vy; s.z += vz; s.w += vw;
        q.x += vx * vx; q.y += vy * vy; q.z += vz * vz; q.w += vw * vw;
    }
    ls[rg][c4] = s;
    lq[rg][c4] = q;
    __syncthreads();
    if (rg == 0) {
#pragma unroll
        for (int i = 1; i < 8; ++i) {
            float4 a = ls[i][c4];
            s.x += a.x; s.y += a.y; s.z += a.z; s.w += a.w;
            float4 b = lq[i][c4];
            q.x += b.x; q.y += b.y; q.z += b.z; q.w += b.w;
        }
        float4* p4 = (float4*)(partial + (size_t)blockIdx.x * 256);
        p4[c4] = s;
        p4[c4 + 32] = q;
    }
}

// ---------------- BN stage 2 + finalize: one block, 1024 threads -------------
__global__ __launch_bounds__(1024) void bn_finalize_kernel(const float* __restrict__ partial,
    float* __restrict__ stats, const float* __restrict__ gamma,
    const float* __restrict__ beta, float invN)
{
    __shared__ float vals[4][256];
    int t = threadIdx.x;
    int c = t & 255;
    int slice = t >> 8;  // 0..3
    float s = 0.f;
#pragma unroll 8
    for (int b = slice * (BNR_GRID / 4); b < (slice + 1) * (BNR_GRID / 4); ++b)
        s += partial[(size_t)b * 256 + c];
    vals[slice][c] = s;
    __syncthreads();
    if (t < 256)
        vals[0][t] = vals[0][t] + vals[1][t] + vals[2][t] + vals[3][t];
    __syncthreads();
    if (t < 128) {
        float mean = vals[0][t] * invN;
        float var = vals[0][t + 128] * invN - mean * mean;
        float inv = rsqrtf(var + BN_EPS);
        float sc = gamma[t] * inv;
        stats[2 * H + t] = sc;
        stats[3 * H + t] = beta[t] - mean * sc;
    }
}

// ---------------- mean-pool fused with final BN-apply + residual -------------
// val = bn(C)*sc+sh + A (no relu, layer L-1); segmented over sorted batch_idx.
#define POOL_ROWS 64
__global__ __launch_bounds__(128) void pool_kernel(const unsigned short* __restrict__ C,
    const float* __restrict__ stats, const unsigned short* __restrict__ A,
    const int* __restrict__ batch, float* __restrict__ pooled,
    float* __restrict__ counts, int N)
{
    int c = threadIdx.x;
    int base = blockIdx.x * POOL_ROWS;
    int end = base + POOL_ROWS;
    if (end > N) end = N;
    if (base >= N) return;
    float sc = stats[2 * H + c];
    float sh = stats[3 * H + c];
    int curg = batch[base];
    int runStart = base;
    float acc = 0.f;
    for (int r = base; r < end; ++r) {
        int g = batch[r];
        if (g != curg) {
            atomicAdd(&pooled[(size_t)curg * H + c], acc);
            if (c == 0) atomicAdd(&counts[curg], (float)(r - runStart));
            curg = g;
            acc = 0.f;
            runStart = r;
        }
        float val = bf16f(C[(size_t)r * H + c]) * sc + sh + bf16f(A[(size_t)r * H + c]);
        acc += val;
    }
    atomicAdd(&pooled[(size_t)curg * H + c], acc);
    if (c == 0) atomicAdd(&counts[curg], (float)(end - runStart));
}

// ---------------- final: sigmoid(mean . linW + b) ----------------------------
__global__ __launch_bounds__(256) void final_kernel(const float* __restrict__ pooled,
    const float* __restrict__ counts, const float* __restrict__ linW,
    const float* __restrict__ linb, float* __restrict__ out, int G)
{
    int g = blockIdx.x * 4 + (threadIdx.x >> 6);
    int lane = threadIdx.x & 63;
    if (g >= G) return;
    float2 p = ((const float2*)(pooled + (size_t)g * H))[lane];
    float2 w = ((const float2*)linW)[lane];
    float part = p.x * w.x + p.y * w.y;
#pragma unroll
    for (int off = 32; off > 0; off >>= 1)
        part += __shfl_down(part, off, 64);
    if (lane == 0) {
        float cnt = fmaxf(counts[g], 1.0f);
        float z = part / cnt + linb[0];
        out[g] = 1.0f / (1.0f + expf(-z));
    }
}

static inline size_t align4(size_t x) { return (x + 3) & ~(size_t)3; }  // 16B align (in floats)

extern "C" void kernel_launch(void* const* d_in, const int* in_sizes, int n_in,
                              void* d_out, int out_size, void* d_ws, size_t ws_size,
                              hipStream_t stream)
{
    const int* x = (const int*)d_in[0];
    const int* ei = (const int*)d_in[1];
    const int* batch = (const int*)d_in[2];
    const float* table = (const float*)d_in[3];
    const float* convW = (const float*)d_in[4];
    const float* convB = (const float*)d_in[5];
    const float* gamma = (const float*)d_in[6];
    const float* beta = (const float*)d_in[7];
    const float* linW = (const float*)d_in[8];
    const float* linb = (const float*)d_in[9];
    float* out = (float*)d_out;

    int N = in_sizes[0] / 9;
    int E = in_sizes[1] / 2;
    int G = out_size;
    int L = in_sizes[4] / (H * H);
    const int* row = ei;
    const int* col = ei + E;
    int NB = (N + 255) / 256;  // blocks for scan (must be <= 512)

    float* ws = (float*)d_ws;
    size_t off = 0;
    // ---- zeroed region ----
    int* deg = (int*)(ws + off);        off = align4(off + N);
    int* cnt = (int*)(ws + off);        off = align4(off + N);
    float* pooled = ws + off;           off = align4(off + (size_t)G * H);
    float* counts = ws + off;           off = align4(off + G);
    float* stats = ws + off;            off = align4(off + (size_t)L * 4 * H);
    size_t zero_bytes = off * sizeof(float);
    // ---- non-zeroed ----
    float* dis = ws + off;              off = align4(off + N);
    int* row_ptr = (int*)(ws + off);    off = align4(off + N + 1);
    int* blockSums = (int*)(ws + off);  off = align4(off + 512);
    float* partial = ws + off;          off = align4(off + (size_t)BNR_GRID * 256);
    unsigned short* wt = (unsigned short*)(ws + off); off = align4(off + (size_t)L * H * H);  // L*2*H*H ushort
    float2* edge_data = (float2*)(ws + off); off = align4(off + (size_t)2 * E);
    unsigned short* A = (unsigned short*)(ws + off); off = align4(off + (size_t)N * H / 2);  // bf16 h
    unsigned short* B = (unsigned short*)(ws + off); off = align4(off + (size_t)N * H / 2);  // bf16 ht
    unsigned short* C = (unsigned short*)(ws + off); off = align4(off + (size_t)N * H / 2);  // bf16 agg

    hipMemsetAsync(d_ws, 0, zero_bytes, stream);

    enc_kernel<<<(N * 32 + 255) / 256, 256, 0, stream>>>(x, table, A, N);
    deg_kernel<<<(E + 255) / 256, 256, 0, stream>>>(col, deg, E);
    scan1_kernel<<<NB, 256, 0, stream>>>(deg, blockSums, N);
    scan2_kernel<<<1, 512, 0, stream>>>(blockSums, NB);
    scan3_kernel<<<NB, 256, 0, stream>>>(deg, blockSums, row_ptr, dis, N, E);
    fill_kernel<<<(E + 255) / 256, 256, 0, stream>>>(row, col, row_ptr, cnt, dis, edge_data, E);
    wprep_kernel<<<L * 128, 128, 0, stream>>>(convW, wt, L);

    int gemmBlocks = (N + 63) / 64;
    for (int l = 0; l < L; ++l) {
        float* st = stats + (size_t)l * 4 * H;
        const float* stPrev = stats + (size_t)(l > 0 ? l - 1 : 0) * 4 * H;
        const unsigned short* wthi = wt + (size_t)l * 2 * H * H;
        gemm_mfma_kernel<<<gemmBlocks, 256, 0, stream>>>(A, C, stPrev, wthi, B, A, N,
                                                         l > 0 ? 1 : 0);
        agg_kernel<<<(N + 3) / 4, 256, 0, stream>>>(B, row_ptr, edge_data, dis,
                                                    convB + (size_t)l * H, C, N);
        bn_reduce_kernel<<<BNR_GRID, 256, 0, stream>>>(C, partial, N);
        bn_finalize_kernel<<<1, 1024, 0, stream>>>(partial, st, gamma + (size_t)l * H,
                                                   beta + (size_t)l * H, 1.0f / (float)N);
    }

    // pool fused with final-layer BN apply + residual (no relu)
    pool_kernel<<<(N + POOL_ROWS - 1) / POOL_ROWS, 128, 0, stream>>>(
        C, stats + (size_t)(L - 1) * 4 * H, A, batch, pooled, counts, N);
    final_kernel<<<(G + 3) / 4, 256, 0, stream>>>(pooled, counts, linW, linb, out, G);
}